// Round 1
// baseline (87.770 us; speedup 1.0000x reference)
//
#include <hip/hip_runtime.h>

// Problem constants (fixed by setup_inputs)
#define BB 2
#define CC 32
#define HH 128
#define WW 256
#define DD 48
#define HW (HH * WW)      // 32768
#define NS 65             // shifts 0..64 (disp in [0,64))
#define PAD 64            // front zero pad of y rows in LDS
#define YROW (PAD + WW)   // 320

// cost[b,d,h,w] = (1/C) * sum_c x[b,c,h,w] * lerp(y[b,c,h,w-s0], y[b,c,h,w-s0+1], ...)
// Factored: corr[s][w] = sum_c x[c,w]*ypad[c][w-s];  out = ((1-fx)*corr[s0] + fx*corr[s0-1])/C
// s0 = ceil(disp), fx = s0 - disp.

__global__ __launch_bounds__(1024) void cost_volume_kernel(
    const float* __restrict__ x, const float* __restrict__ y,
    const float* __restrict__ disp, float* __restrict__ out) {
  __shared__ float xs[CC * WW];       //  32 KB
  __shared__ float ys[CC * YROW];     //  40 KB (first PAD floats of each row = 0)
  __shared__ float corr[NS * WW];     //  65 KB

  const int bx = blockIdx.x;
  const int b = bx >> 7;   // / HH
  const int h = bx & 127;
  const int tid = threadIdx.x;

  // ---------------- Phase 1: stage x row and zero-padded y row ----------------
  const int gbase = (b * CC * HH + h) * WW;  // + c*HW + w
  if (tid < 512) {  // zero the pad: 32 rows * 64 floats = 2048 floats = 512 f4
    int c = tid >> 4;
    int j = (tid & 15) << 2;
    *(float4*)&ys[c * YROW + j] = make_float4(0.f, 0.f, 0.f, 0.f);
  }
#pragma unroll
  for (int k = 0; k < 2; ++k) {
    int t = tid + (k << 10);       // 0..2047
    int c = t >> 6;                // 64 float4 per row
    int w = (t & 63) << 2;
    float4 vx = *(const float4*)(x + gbase + c * HW + w);
    float4 vy = *(const float4*)(y + gbase + c * HW + w);
    *(float4*)&xs[c * WW + w] = vx;
    *(float4*)&ys[c * YROW + PAD + w] = vy;
  }
  __syncthreads();

  // ---------------- Phase 2: corr[s][w] = sum_c xs[c][w] * ypad[c][w-s] -------
  const int wid = tid >> 6;
  const int lane = tid & 63;
  const int w0 = lane << 2;  // each lane owns 4 consecutive w

  if (wid < 8) {
    const int g = wid;  // shift group: s in [8g, 8g+7]
    float acc[8][4];
#pragma unroll
    for (int sl = 0; sl < 8; ++sl)
#pragma unroll
      for (int wj = 0; wj < 4; ++wj) acc[sl][wj] = 0.f;

    // window index needed: PAD + (w0+wj) - (8g+sl), sl 0..7, wj 0..3
    // => [base-7, base+3] with base = PAD + w0 - 8g.  Aligned A = base - 8.
    const int A = PAD + w0 - 8 * g - 8;  // multiple of 4, >= 0 (g<=7)
#pragma unroll 4
    for (int c = 0; c < CC; ++c) {
      float4 xv = *(const float4*)&xs[c * WW + w0];
      const float* yrow = &ys[c * YROW];
      float4 wv0 = *(const float4*)&yrow[A];
      float4 wv1 = *(const float4*)&yrow[A + 4];
      float4 wv2 = *(const float4*)&yrow[A + 8];
      float win[12] = {wv0.x, wv0.y, wv0.z, wv0.w, wv1.x, wv1.y,
                       wv1.z, wv1.w, wv2.x, wv2.y, wv2.z, wv2.w};
      float xr[4] = {xv.x, xv.y, xv.z, xv.w};
#pragma unroll
      for (int sl = 0; sl < 8; ++sl)
#pragma unroll
        for (int wj = 0; wj < 4; ++wj)
          acc[sl][wj] = fmaf(xr[wj], win[8 + wj - sl], acc[sl][wj]);
    }
#pragma unroll
    for (int sl = 0; sl < 8; ++sl)
      *(float4*)&corr[(8 * g + sl) * WW + w0] =
          make_float4(acc[sl][0], acc[sl][1], acc[sl][2], acc[sl][3]);
  } else if (wid == 8) {
    // s = 64 row
    float acc[4] = {0.f, 0.f, 0.f, 0.f};
#pragma unroll 4
    for (int c = 0; c < CC; ++c) {
      float4 xv = *(const float4*)&xs[c * WW + w0];
      float4 yv = *(const float4*)&ys[c * YROW + w0];  // PAD + w - 64 = w0+wj
      acc[0] = fmaf(xv.x, yv.x, acc[0]);
      acc[1] = fmaf(xv.y, yv.y, acc[1]);
      acc[2] = fmaf(xv.z, yv.z, acc[2]);
      acc[3] = fmaf(xv.w, yv.w, acc[3]);
    }
    *(float4*)&corr[64 * WW + w0] = make_float4(acc[0], acc[1], acc[2], acc[3]);
  }
  __syncthreads();

  // ---------------- Phase 3: per-output lerp over corr ------------------------
  const float inv_c = 1.0f / (float)CC;
  const float* dbase = disp + (b * DD * HH + h) * WW;  // + d*HW + w
  float* obase = out + (b * DD * HH + h) * WW;
#pragma unroll
  for (int k = 0; k < (DD * WW) / 1024; ++k) {  // 12 iters
    int idx = tid + (k << 10);
    int d = idx >> 8;   // / WW
    int w = idx & 255;
    float dv = dbase[d * HW + w];
    float s0f = ceilf(dv);
    int i0 = (int)s0f;
    float fx = s0f - dv;           // in [0,1)
    int i1 = (i0 > 0) ? i0 - 1 : 0;  // i0==0 => fx==0, weight-0 read
    float c0 = corr[i0 * WW + w];    // lanes vary w: stride-256 rows => conflict-free
    float c1 = corr[i1 * WW + w];
    obase[d * HW + w] = (c0 + fx * (c1 - c0)) * inv_c;
  }
}

extern "C" void kernel_launch(void* const* d_in, const int* in_sizes, int n_in,
                              void* d_out, int out_size, void* d_ws, size_t ws_size,
                              hipStream_t stream) {
  const float* x = (const float*)d_in[0];
  const float* y = (const float*)d_in[1];
  const float* disp = (const float*)d_in[2];
  float* out = (float*)d_out;
  cost_volume_kernel<<<BB * HH, 1024, 0, stream>>>(x, y, disp, out);
}